// Round 6
// baseline (422.044 us; speedup 1.0000x reference)
//
#include <hip/hip_runtime.h>
#include <hip/hip_bf16.h>

static constexpr int Hh = 56, Wd = 56, HWsz = 3136;
static constexpr float EPS = 1e-5f;

// Force a VECTOR (global_load) path for wave-uniform addresses.
// Pins the pointer in a VGPR so the compiler cannot prove scalar-ness and
// emit s_load (SMEM completes out-of-order vs DS in lgkmcnt -> any s_load
// use forces lgkmcnt(0), draining all LDS prefetch).
__device__ __forceinline__ float4 vload4(const float* p) {
    const float4* q = reinterpret_cast<const float4*>(p);
    asm volatile("" : "+v"(q));
    return *q;
}
__device__ __forceinline__ float vload1(const float* p) {
    asm volatile("" : "+v"(p));
    return *p;
}

// ---------------------------------------------------------------------------
// prep: transpose weights so inner loops read contiguous 16B runs.
// ---------------------------------------------------------------------------
__global__ __launch_bounds__(256) void prep_transpose(
    const float* __restrict__ w1, const float* __restrict__ w3,
    const float* __restrict__ c1w,
    float* __restrict__ w1t, float* __restrict__ w3t, float* __restrict__ c1wt)
{
    const int idx = blockIdx.x * 256 + threadIdx.x;   // grid 64 -> 16384
    {
        const int c = idx >> 6, o = idx & 63;
        w1t[idx] = w1[o * 256 + c];
    }
    {
        const int c = idx >> 8, o = idx & 255;
        w3t[idx] = w3[o * 64 + c];
    }
    if (idx < 1024) {
        const int c = idx >> 4, g = idx & 15;
        c1wt[idx] = c1w[g * 64 + c];
    }
}

// ---------------------------------------------------------------------------
// K1: conv1 (1x1, 256->64) + BN1 + ReLU -> out1; t = relu(bn(c1w@out1)) -> tbuf
// 256 thr = 4 waves; tile 64 px x 64 out; thread = 1 px x 16 outs.
// Weights via forced-vector float4 loads (vmcnt path, L1-hot). Next chunk's
// x loads issue before the compute loop (vmcnt prefetch over FMA block).
// ---------------------------------------------------------------------------
__global__ __launch_bounds__(256) void k1_conv1_branch(
    const float* __restrict__ x,
    const float* __restrict__ w1t,
    const float* __restrict__ bn1g, const float* __restrict__ bn1b,
    const float* __restrict__ bn1m, const float* __restrict__ bn1v,
    const float* __restrict__ c1wt,
    const float* __restrict__ ibg, const float* __restrict__ ibb,
    const float* __restrict__ ibm, const float* __restrict__ ibv,
    float* __restrict__ out1, float* __restrict__ tbuf)
{
    __shared__ float lds[64 * 64];   // 16 KB [channel][pixel]
    const int tid  = threadIdx.x;
    const int lane = tid & 63;
    const int wv   = tid >> 6;       // 0..3
    const int pix0 = blockIdx.x * 64;
    const int b    = pix0 / HWsz;
    const int hw0  = pix0 - b * HWsz;
    const float* xb = x + (size_t)b * 256 * HWsz + hw0 + lane;
    const int o0 = wv * 16;

    float acc[16];
#pragma unroll
    for (int i = 0; i < 16; ++i) acc[i] = 0.f;

    // prologue: fetch chunk 0
    float r[16];
#pragma unroll
    for (int i = 0; i < 16; ++i)
        r[i] = xb[(size_t)(wv * 16 + i) * HWsz];

#pragma unroll 1
    for (int k = 0; k < 4; ++k) {
        __syncthreads();
#pragma unroll
        for (int i = 0; i < 16; ++i)
            lds[(wv * 16 + i) * 64 + lane] = r[i];
        __syncthreads();
        if (k < 3) {   // prefetch next chunk: overlaps the FMA block below
#pragma unroll
            for (int i = 0; i < 16; ++i)
                r[i] = xb[(size_t)((k + 1) * 64 + wv * 16 + i) * HWsz];
        }
#pragma unroll 4
        for (int c = 0; c < 64; ++c) {
            const float xv = lds[c * 64 + lane];
            const float* wp = w1t + (size_t)(k * 64 + c) * 64 + o0;
            const float4 wA = vload4(wp);
            const float4 wB = vload4(wp + 4);
            const float4 wC = vload4(wp + 8);
            const float4 wD = vload4(wp + 12);
            acc[0]  = fmaf(wA.x, xv, acc[0]);
            acc[1]  = fmaf(wA.y, xv, acc[1]);
            acc[2]  = fmaf(wA.z, xv, acc[2]);
            acc[3]  = fmaf(wA.w, xv, acc[3]);
            acc[4]  = fmaf(wB.x, xv, acc[4]);
            acc[5]  = fmaf(wB.y, xv, acc[5]);
            acc[6]  = fmaf(wB.z, xv, acc[6]);
            acc[7]  = fmaf(wB.w, xv, acc[7]);
            acc[8]  = fmaf(wC.x, xv, acc[8]);
            acc[9]  = fmaf(wC.y, xv, acc[9]);
            acc[10] = fmaf(wC.z, xv, acc[10]);
            acc[11] = fmaf(wC.w, xv, acc[11]);
            acc[12] = fmaf(wD.x, xv, acc[12]);
            acc[13] = fmaf(wD.y, xv, acc[13]);
            acc[14] = fmaf(wD.z, xv, acc[14]);
            acc[15] = fmaf(wD.w, xv, acc[15]);
        }
    }
    __syncthreads();

    // BN1 + ReLU; write out1 and restage tile for the branch
    {
        float* o1p = out1 + (size_t)b * 64 * HWsz + hw0 + lane;
#pragma unroll
        for (int i = 0; i < 16; ++i) {
            const int o = o0 + i;
            const float s = bn1g[o] * rsqrtf(bn1v[o] + EPS);
            const float v = fmaxf(fmaf(acc[i], s, bn1b[o] - bn1m[o] * s), 0.f);
            lds[o * 64 + lane] = v;
            o1p[(size_t)o * HWsz] = v;
        }
    }
    __syncthreads();

    // t: wave wv computes g = 4*wv .. 4*wv+3
    const int g0 = wv * 4;
    float ta[4];
#pragma unroll
    for (int i = 0; i < 4; ++i) ta[i] = 0.f;
#pragma unroll 8
    for (int c = 0; c < 64; ++c) {
        const float v = lds[c * 64 + lane];
        const float4 cw = vload4(c1wt + c * 16 + g0);
        ta[0] = fmaf(cw.x, v, ta[0]);
        ta[1] = fmaf(cw.y, v, ta[1]);
        ta[2] = fmaf(cw.z, v, ta[2]);
        ta[3] = fmaf(cw.w, v, ta[3]);
    }
    {
        float* tp = tbuf + ((size_t)b * 16 + g0) * HWsz + hw0 + lane;
#pragma unroll
        for (int i = 0; i < 4; ++i) {
            const int g = g0 + i;
            const float s = ibg[g] * rsqrtf(ibv[g] + EPS);
            tp[(size_t)i * HWsz] = fmaxf(fmaf(ta[i], s, ibb[g] - ibm[g] * s), 0.f);
        }
    }
}

// ---------------------------------------------------------------------------
// K2: involution (K=7, pad=3) + BN2 + ReLU, weights generated inline from t.
// grid (7 x 64 bg x 2 ch-halves), block 448 = 8 rows x 56 cols, 1 px/thread.
// Halo in LDS (28 KB); c2w/c2b via forced-vector global loads (L1-hot,
// vmcnt path) so the LDS pipe serves only the halo reads.
// ---------------------------------------------------------------------------
__global__ __launch_bounds__(448) void k2_involution(
    const float* __restrict__ out1, const float* __restrict__ tbuf,
    const float* __restrict__ c2w, const float* __restrict__ c2b,
    const float* __restrict__ bn2g, const float* __restrict__ bn2b,
    const float* __restrict__ bn2m, const float* __restrict__ bn2v,
    float* __restrict__ out2)
{
    __shared__ float lds[8 * 14 * 64];   // 28 KB: 8 ch x (8+6) rows x 64 stride
    const int r0   = blockIdx.x * 8;     // 7 tiles x 8 rows = 56 exact
    const int b    = blockIdx.y >> 2, g = blockIdx.y & 3;
    const int ch0  = g * 16 + blockIdx.z * 8;

    const int tid = threadIdx.x;
    const int row = tid / 56;            // 0..7
    const int col = tid - row * 56;      // 0..55
    const int hw  = (r0 + row) * Wd + col;

    // stage halo: 8 channels x 14 rows x 62 cols (stride 64)
    const float* src = out1 + ((size_t)b * 64 + ch0) * HWsz;
#pragma unroll
    for (int c = 0; c < 8; ++c) {
        for (int idx = tid; idx < 14 * 64; idx += 448) {
            const int rr = idx >> 6, cc = idx & 63;
            const int gr = r0 + rr - 3, gc = cc - 3;
            float v = 0.f;
            if (cc < 62 && gr >= 0 && gr < Hh && gc >= 0 && gc < Wd)
                v = src[(size_t)c * HWsz + gr * Wd + gc];
            lds[(c * 14 + rr) * 64 + cc] = v;
        }
    }

    // per-pixel t (16 values)
    float tv[16];
    {
        const float* tp = tbuf + (size_t)b * 16 * HWsz + hw;
#pragma unroll
        for (int q = 0; q < 16; ++q)
            tv[q] = tp[(size_t)q * HWsz];
    }
    __syncthreads();

    float acc[8];
#pragma unroll
    for (int i = 0; i < 8; ++i) acc[i] = 0.f;

#pragma unroll
    for (int kh = 0; kh < 7; ++kh) {
        // materialize this kh-row's 7 per-pixel weights from t
        float wk[7];
#pragma unroll
        for (int kw = 0; kw < 7; ++kw) {
            const int j = g * 49 + kh * 7 + kw;
            const float* cw = c2w + j * 16;
            const float4 q0 = vload4(cw);
            const float4 q1 = vload4(cw + 4);
            const float4 q2 = vload4(cw + 8);
            const float4 q3 = vload4(cw + 12);
            float a = vload1(c2b + j);
            a = fmaf(q0.x, tv[0],  a); a = fmaf(q0.y, tv[1],  a);
            a = fmaf(q0.z, tv[2],  a); a = fmaf(q0.w, tv[3],  a);
            a = fmaf(q1.x, tv[4],  a); a = fmaf(q1.y, tv[5],  a);
            a = fmaf(q1.z, tv[6],  a); a = fmaf(q1.w, tv[7],  a);
            a = fmaf(q2.x, tv[8],  a); a = fmaf(q2.y, tv[9],  a);
            a = fmaf(q2.z, tv[10], a); a = fmaf(q2.w, tv[11], a);
            a = fmaf(q3.x, tv[12], a); a = fmaf(q3.y, tv[13], a);
            a = fmaf(q3.z, tv[14], a); a = fmaf(q3.w, tv[15], a);
            wk[kw] = a;
        }
#pragma unroll
        for (int c8 = 0; c8 < 8; ++c8) {
            const float* lrow = &lds[(c8 * 14 + row + kh) * 64 + col];
#pragma unroll
            for (int kw = 0; kw < 7; ++kw)
                acc[c8] = fmaf(wk[kw], lrow[kw], acc[c8]);
        }
    }

    float* op = out2 + ((size_t)b * 64 + ch0) * HWsz + hw;
#pragma unroll
    for (int i = 0; i < 8; ++i) {
        const int ch = ch0 + i;
        const float s   = bn2g[ch] * rsqrtf(bn2v[ch] + EPS);
        const float off = bn2b[ch] - bn2m[ch] * s;
        op[(size_t)i * HWsz] = fmaxf(fmaf(acc[i], s, off), 0.f);
    }
}

// ---------------------------------------------------------------------------
// K3: conv3 (1x1, 64->256) + BN3 + residual + ReLU
// grid (784,4), 256 thr = 4 waves; tile 64 px x 64 outs; thread = 1 px x 16.
// Weights via forced-vector float4 (vmcnt); residual prefetched over GEMM.
// ---------------------------------------------------------------------------
__global__ __launch_bounds__(256) void k3_conv3(
    const float* __restrict__ out2, const float* __restrict__ x,
    const float* __restrict__ w3t,
    const float* __restrict__ bn3g, const float* __restrict__ bn3b,
    const float* __restrict__ bn3m, const float* __restrict__ bn3v,
    float* __restrict__ out)
{
    __shared__ float lds[64 * 64];   // 16 KB
    const int tid  = threadIdx.x;
    const int lane = tid & 63;
    const int wv   = tid >> 6;       // 0..3
    const int pix0 = blockIdx.x * 64;
    const int b    = pix0 / HWsz;
    const int hw0  = pix0 - b * HWsz;

    const float* ip = out2 + (size_t)b * 64 * HWsz + hw0 + lane;
#pragma unroll
    for (int i = 0; i < 16; ++i) {
        const int ch = wv * 16 + i;
        lds[ch * 64 + lane] = ip[(size_t)ch * HWsz];
    }
    __syncthreads();

    const int o0 = blockIdx.y * 64 + wv * 16;

    // residual prefetch: 16 streaming loads in flight during the GEMM loop
    const float* xp = x + ((size_t)b * 256 + o0) * HWsz + hw0 + lane;
    float xr[16];
#pragma unroll
    for (int i = 0; i < 16; ++i) xr[i] = xp[(size_t)i * HWsz];

    float acc[16];
#pragma unroll
    for (int i = 0; i < 16; ++i) acc[i] = 0.f;

#pragma unroll 4
    for (int c = 0; c < 64; ++c) {
        const float xv = lds[c * 64 + lane];
        const float* wp = w3t + (size_t)c * 256 + o0;
        const float4 wA = vload4(wp);
        const float4 wB = vload4(wp + 4);
        const float4 wC = vload4(wp + 8);
        const float4 wD = vload4(wp + 12);
        acc[0]  = fmaf(wA.x, xv, acc[0]);
        acc[1]  = fmaf(wA.y, xv, acc[1]);
        acc[2]  = fmaf(wA.z, xv, acc[2]);
        acc[3]  = fmaf(wA.w, xv, acc[3]);
        acc[4]  = fmaf(wB.x, xv, acc[4]);
        acc[5]  = fmaf(wB.y, xv, acc[5]);
        acc[6]  = fmaf(wB.z, xv, acc[6]);
        acc[7]  = fmaf(wB.w, xv, acc[7]);
        acc[8]  = fmaf(wC.x, xv, acc[8]);
        acc[9]  = fmaf(wC.y, xv, acc[9]);
        acc[10] = fmaf(wC.z, xv, acc[10]);
        acc[11] = fmaf(wC.w, xv, acc[11]);
        acc[12] = fmaf(wD.x, xv, acc[12]);
        acc[13] = fmaf(wD.y, xv, acc[13]);
        acc[14] = fmaf(wD.z, xv, acc[14]);
        acc[15] = fmaf(wD.w, xv, acc[15]);
    }

    float* op = out + ((size_t)b * 256 + o0) * HWsz + hw0 + lane;
#pragma unroll 4
    for (int i = 0; i < 16; ++i) {
        const int o = o0 + i;
        const float s   = bn3g[o] * rsqrtf(bn3v[o] + EPS);
        const float off = bn3b[o] - bn3m[o] * s;
        const float val = fmaf(acc[i], s, off) + xr[i];
        op[(size_t)i * HWsz] = fmaxf(val, 0.f);
    }
}

extern "C" void kernel_launch(void* const* d_in, const int* in_sizes, int n_in,
                              void* d_out, int out_size, void* d_ws, size_t ws_size,
                              hipStream_t stream)
{
    const float* x    = (const float*)d_in[0];
    const float* w1   = (const float*)d_in[1];
    const float* bn1g = (const float*)d_in[2];
    const float* bn1b = (const float*)d_in[3];
    const float* bn1m = (const float*)d_in[4];
    const float* bn1v = (const float*)d_in[5];
    const float* c1w  = (const float*)d_in[6];
    const float* ibg  = (const float*)d_in[7];
    const float* ibb  = (const float*)d_in[8];
    const float* ibm  = (const float*)d_in[9];
    const float* ibv  = (const float*)d_in[10];
    const float* c2w  = (const float*)d_in[11];
    const float* c2b  = (const float*)d_in[12];
    const float* bn2g = (const float*)d_in[13];
    const float* bn2b = (const float*)d_in[14];
    const float* bn2m = (const float*)d_in[15];
    const float* bn2v = (const float*)d_in[16];
    const float* w3   = (const float*)d_in[17];
    const float* bn3g = (const float*)d_in[18];
    const float* bn3b = (const float*)d_in[19];
    const float* bn3m = (const float*)d_in[20];
    const float* bn3v = (const float*)d_in[21];

    // ws (floats): out1 [0, 3211264) | out2 [3211264, 6422528)
    //              w1t 16384 | w3t 16384 | c1wt 1024
    float* out1 = (float*)d_ws;
    float* out2 = (float*)d_ws + 3211264;
    float* w1t  = (float*)d_ws + 6422528;
    float* w3t  = w1t + 16384;
    float* c1wt = w3t + 16384;
    // t [16,16,3136] fp32 (3.2 MB) lives in d_out — dead before k3 writes out
    float* tbuf = (float*)d_out;

    prep_transpose<<<dim3(64), dim3(256), 0, stream>>>(w1, w3, c1w, w1t, w3t, c1wt);

    k1_conv1_branch<<<dim3(784), dim3(256), 0, stream>>>(
        x, w1t, bn1g, bn1b, bn1m, bn1v, c1wt, ibg, ibb, ibm, ibv,
        out1, tbuf);

    k2_involution<<<dim3(7, 64, 2), dim3(448), 0, stream>>>(
        out1, tbuf, c2w, c2b, bn2g, bn2b, bn2m, bn2v, out2);

    k3_conv3<<<dim3(784, 4), dim3(256), 0, stream>>>(
        out2, x, w3t, bn3g, bn3b, bn3m, bn3v, (float*)d_out);
}

// Round 7
// 196.386 us; speedup vs baseline: 2.1491x; 2.1491x over previous
//
#include <hip/hip_runtime.h>
#include <hip/hip_bf16.h>

typedef __attribute__((ext_vector_type(8))) short short8;
typedef __attribute__((ext_vector_type(4))) float floatx4;

static constexpr int Hh = 56, Wd = 56, HWsz = 3136;
static constexpr float EPS = 1e-5f;

__device__ __forceinline__ unsigned short f2bf(float f) {
    __hip_bfloat16 h = __float2bfloat16(f);
    return *reinterpret_cast<unsigned short*>(&h);
}
__device__ __forceinline__ unsigned pack2(float a, float b) {
    return (unsigned)f2bf(a) | ((unsigned)f2bf(b) << 16);
}
__device__ __forceinline__ short8 as_short8(uint4 v) {
    union { uint4 u; short8 s; } c; c.u = v; return c.s;
}

// ---------------------------------------------------------------------------
// prep: pack weights into MFMA A-fragment order (bf16) + fold BN affines.
// A-frag layout per 16x16x32 wave: m = lane&15, k = (lane>>4)*8 + j (j 0..7).
// w1p[((mb*8+ks)*64+lane)*8+j]  (64x256)   w3p[((mb*2+ks)*64+lane)*8+j] (256x64)
// c1wp[((ks)*64+lane)*8+j]      (16x64)
// ---------------------------------------------------------------------------
__global__ __launch_bounds__(256) void prep(
    const float* __restrict__ w1, const float* __restrict__ w3,
    const float* __restrict__ c1w,
    const float* __restrict__ bn1g, const float* __restrict__ bn1b,
    const float* __restrict__ bn1m, const float* __restrict__ bn1v,
    const float* __restrict__ ibg, const float* __restrict__ ibb,
    const float* __restrict__ ibm, const float* __restrict__ ibv,
    const float* __restrict__ bn2g, const float* __restrict__ bn2b,
    const float* __restrict__ bn2m, const float* __restrict__ bn2v,
    const float* __restrict__ bn3g, const float* __restrict__ bn3b,
    const float* __restrict__ bn3m, const float* __restrict__ bn3v,
    unsigned short* __restrict__ w1p, unsigned short* __restrict__ w3p,
    unsigned short* __restrict__ c1wp,
    float* __restrict__ bn1s, float* __restrict__ bn1o,
    float* __restrict__ ibs,  float* __restrict__ ibo,
    float* __restrict__ bn2s, float* __restrict__ bn2o,
    float* __restrict__ bn3s, float* __restrict__ bn3o)
{
    const int idx = blockIdx.x * 256 + threadIdx.x;   // grid 64 -> 16384
    {
        const int j = idx & 7, ln = (idx >> 3) & 63, ks = (idx >> 9) & 7, mb = idx >> 12;
        const int m = mb * 16 + (ln & 15), k = ks * 32 + ((ln >> 4) & 3) * 8 + j;
        w1p[idx] = f2bf(w1[m * 256 + k]);
    }
    {
        const int j = idx & 7, ln = (idx >> 3) & 63, ks = (idx >> 9) & 1, mb = idx >> 10;
        const int m = mb * 16 + (ln & 15), k = ks * 32 + ((ln >> 4) & 3) * 8 + j;
        w3p[idx] = f2bf(w3[m * 64 + k]);
    }
    if (idx < 1024) {
        const int j = idx & 7, ln = (idx >> 3) & 63, ks = idx >> 9;
        const int m = ln & 15, k = ks * 32 + ((ln >> 4) & 3) * 8 + j;
        c1wp[idx] = f2bf(c1w[m * 64 + k]);
    }
    if (idx < 64)  { float s = bn1g[idx] * rsqrtf(bn1v[idx] + EPS); bn1s[idx] = s; bn1o[idx] = bn1b[idx] - bn1m[idx] * s; }
    if (idx < 16)  { float s = ibg[idx]  * rsqrtf(ibv[idx]  + EPS); ibs[idx]  = s; ibo[idx]  = ibb[idx]  - ibm[idx]  * s; }
    if (idx < 64)  { float s = bn2g[idx] * rsqrtf(bn2v[idx] + EPS); bn2s[idx] = s; bn2o[idx] = bn2b[idx] - bn2m[idx] * s; }
    if (idx < 256) { float s = bn3g[idx] * rsqrtf(bn3v[idx] + EPS); bn3s[idx] = s; bn3o[idx] = bn3b[idx] - bn3m[idx] * s; }
}

// ---------------------------------------------------------------------------
// K1: conv1 via MFMA (M=64 ch, K=256, N=64 px/block) + BN1 + ReLU -> out1 fp32
// [ch][px]; fused branch: tile -> bf16 LDS -> MFMA (M=16, K=64) -> t -> tbuf.
// 256 thr = 4 waves; wave wv owns ch-rows wv*16.., iterates 4 px-subtiles.
// ---------------------------------------------------------------------------
__global__ __launch_bounds__(256) void k1_conv1_branch(
    const float* __restrict__ x, const unsigned short* __restrict__ w1p,
    const float* __restrict__ bn1s, const float* __restrict__ bn1o,
    const unsigned short* __restrict__ c1wp,
    const float* __restrict__ ibs, const float* __restrict__ ibo,
    float* __restrict__ out1, float* __restrict__ tbuf)
{
    __shared__ unsigned short xls[64 * 264];   // 33 KB: [px][c] bf16, stride 264
    __shared__ unsigned short tls[64 * 72];    // 9 KB:  [px][ch] bf16, stride 72
    const int tid  = threadIdx.x;
    const int lane = tid & 63;
    const int n    = lane & 15;
    const int quad = lane >> 4;
    const int wv   = tid >> 6;
    const int pix0 = blockIdx.x * 64;
    const int b    = pix0 / HWsz;
    const int hw0  = pix0 - b * HWsz;

    // stage x: thread (p16, cq) covers px = wv*16+p16, channel-pairs cq+4i
    {
        const int p16 = tid & 15;
        const int cq  = (tid >> 4) & 3;
        const int px  = wv * 16 + p16;
        const float* xb = x + (size_t)b * 256 * HWsz + hw0 + px;
        unsigned short* dst = xls + px * 264;
#pragma unroll 8
        for (int i = 0; i < 32; ++i) {
            const int cp = cq + 4 * i;
            const float v0 = xb[(size_t)(2 * cp) * HWsz];
            const float v1 = xb[(size_t)(2 * cp + 1) * HWsz];
            *reinterpret_cast<unsigned*>(dst + 2 * cp) = pack2(v0, v1);
        }
    }

    // A fragments (this wave's 16 output channels, full K=256)
    short8 afr[8];
    {
        const uint4* wp = reinterpret_cast<const uint4*>(w1p);
#pragma unroll
        for (int ks = 0; ks < 8; ++ks)
            afr[ks] = as_short8(wp[(wv * 8 + ks) * 64 + lane]);
    }
    __syncthreads();

    const floatx4 zero = {0.f, 0.f, 0.f, 0.f};
    floatx4 acc[4];
#pragma unroll
    for (int nt = 0; nt < 4; ++nt) acc[nt] = zero;

#pragma unroll
    for (int nt = 0; nt < 4; ++nt) {
        const unsigned short* bp = xls + (nt * 16 + n) * 264 + quad * 8;
#pragma unroll
        for (int ks = 0; ks < 8; ++ks) {
            const short8 bfr = *reinterpret_cast<const short8*>(bp + ks * 32);
            acc[nt] = __builtin_amdgcn_mfma_f32_16x16x32_bf16(afr[ks], bfr, acc[nt], 0, 0, 0);
        }
    }

    // epilogue: BN1 + ReLU; out1 fp32 [ch][px]; tile -> tls bf16 [px][ch]
    const int och = wv * 16 + quad * 4;
    float sr[4], og[4];
#pragma unroll
    for (int r = 0; r < 4; ++r) { sr[r] = bn1s[och + r]; og[r] = bn1o[och + r]; }
#pragma unroll
    for (int nt = 0; nt < 4; ++nt) {
        float f[4];
#pragma unroll
        for (int r = 0; r < 4; ++r)
            f[r] = fmaxf(fmaf(acc[nt][r], sr[r], og[r]), 0.f);
        const int px = nt * 16 + n;
        float* op = out1 + ((size_t)b * 64 + och) * HWsz + hw0 + px;
        op[0] = f[0]; op[HWsz] = f[1]; op[2 * HWsz] = f[2]; op[3 * HWsz] = f[3];
        uint2 pk;
        pk.x = pack2(f[0], f[1]);
        pk.y = pack2(f[2], f[3]);
        *reinterpret_cast<uint2*>(tls + px * 72 + och) = pk;
    }
    __syncthreads();

    // branch: t = relu(bn(c1w @ out1_tile)); wave wv does px-subtile wv
    floatx4 tacc = zero;
    {
        const uint4* cp4 = reinterpret_cast<const uint4*>(c1wp);
        const unsigned short* bp = tls + (wv * 16 + n) * 72 + quad * 8;
#pragma unroll
        for (int ks = 0; ks < 2; ++ks) {
            const short8 af = as_short8(cp4[ks * 64 + lane]);
            const short8 bf = *reinterpret_cast<const short8*>(bp + ks * 32);
            tacc = __builtin_amdgcn_mfma_f32_16x16x32_bf16(af, bf, tacc, 0, 0, 0);
        }
    }
    {
        const int g0 = quad * 4;
        float* tp = tbuf + ((size_t)b * 16 + g0) * HWsz + hw0 + wv * 16 + n;
#pragma unroll
        for (int r = 0; r < 4; ++r)
            tp[(size_t)r * HWsz] = fmaxf(fmaf(tacc[r], ibs[g0 + r], ibo[g0 + r]), 0.f);
    }
}

// ---------------------------------------------------------------------------
// K2: involution + BN2 + ReLU. grid (7, 64 bg, 2 halves), 448 thr, 1 px/thr.
// wk[49] computed ONCE per thread (s_loads isolated from ds_reads); halo LDS
// channel-last [14][62][12] -> inner loop = 2x ds_read_b128 + 8 FMA per tap.
// Output bf16 [b][px][ch] (k3's B-operand layout), 16B stores.
// ---------------------------------------------------------------------------
__global__ __launch_bounds__(448) void k2_involution(
    const float* __restrict__ out1, const float* __restrict__ tbuf,
    const float* __restrict__ c2w, const float* __restrict__ c2b,
    const float* __restrict__ bn2s, const float* __restrict__ bn2o,
    unsigned short* __restrict__ out2b)
{
    __shared__ float lds[14 * 62 * 12];   // 41.7 KB
    const int r0  = blockIdx.x * 8;
    const int b   = blockIdx.y >> 2, g = blockIdx.y & 3;
    const int ch0 = g * 16 + blockIdx.z * 8;
    const int tid = threadIdx.x;
    const int row = tid / 56;
    const int col = tid - row * 56;
    const int hw  = (r0 + row) * Wd + col;

    // halo staging: [rr][cc][c] fp32, pixel stride 12 floats (48B)
    const float* src = out1 + ((size_t)b * 64 + ch0) * HWsz;
    for (int idx = tid; idx < 14 * 62; idx += 448) {
        const int rr = idx / 62, cc = idx - rr * 62;
        const int gr = r0 + rr - 3, gc = cc - 3;
        const bool in = (gr >= 0) & (gr < Hh) & (gc >= 0) & (gc < Wd);
        float* d = &lds[idx * 12];
        const float* s = src + gr * Wd + gc;
#pragma unroll
        for (int c = 0; c < 8; ++c)
            d[c] = in ? s[(size_t)c * HWsz] : 0.f;
    }

    // per-pixel t, then all 49 weights (pure VALU + s_load, no LDS)
    float tv[16];
    {
        const float* tp = tbuf + (size_t)b * 16 * HWsz + hw;
#pragma unroll
        for (int q = 0; q < 16; ++q) tv[q] = tp[(size_t)q * HWsz];
    }
    float wk[49];
    {
        const float* cwb = c2w + g * 49 * 16;
        const float* cbb = c2b + g * 49;
#pragma unroll
        for (int j = 0; j < 49; ++j) {
            float a = cbb[j];
#pragma unroll
            for (int q = 0; q < 16; ++q)
                a = fmaf(cwb[j * 16 + q], tv[q], a);
            wk[j] = a;
        }
    }
    __syncthreads();

    float acc[8];
#pragma unroll
    for (int i = 0; i < 8; ++i) acc[i] = 0.f;

#pragma unroll
    for (int kh = 0; kh < 7; ++kh) {
#pragma unroll
        for (int kw = 0; kw < 7; ++kw) {
            const float* p = &lds[((row + kh) * 62 + (col + kw)) * 12];
            const float4 a0 = *reinterpret_cast<const float4*>(p);
            const float4 a1 = *reinterpret_cast<const float4*>(p + 4);
            const float w = wk[kh * 7 + kw];
            acc[0] = fmaf(w, a0.x, acc[0]);
            acc[1] = fmaf(w, a0.y, acc[1]);
            acc[2] = fmaf(w, a0.z, acc[2]);
            acc[3] = fmaf(w, a0.w, acc[3]);
            acc[4] = fmaf(w, a1.x, acc[4]);
            acc[5] = fmaf(w, a1.y, acc[5]);
            acc[6] = fmaf(w, a1.z, acc[6]);
            acc[7] = fmaf(w, a1.w, acc[7]);
        }
    }

    float f[8];
#pragma unroll
    for (int i = 0; i < 8; ++i)
        f[i] = fmaxf(fmaf(acc[i], bn2s[ch0 + i], bn2o[ch0 + i]), 0.f);
    uint4 pk;
    pk.x = pack2(f[0], f[1]); pk.y = pack2(f[2], f[3]);
    pk.z = pack2(f[4], f[5]); pk.w = pack2(f[6], f[7]);
    *reinterpret_cast<uint4*>(out2b + ((size_t)b * HWsz + hw) * 64 + ch0) = pk;
}

// ---------------------------------------------------------------------------
// K3: conv3 via MFMA (M=256, K=64, N=64 px/block) + BN3 + residual + ReLU.
// 256 thr = 4 waves; wave wv owns px-subtile wv, full M=256 (16 m-tiles).
// ---------------------------------------------------------------------------
__global__ __launch_bounds__(256) void k3_conv3(
    const unsigned short* __restrict__ out2b, const float* __restrict__ x,
    const unsigned short* __restrict__ w3p,
    const float* __restrict__ bn3s, const float* __restrict__ bn3o,
    float* __restrict__ out)
{
    __shared__ unsigned short bls[64 * 72];   // 9 KB bf16 [px][ch]
    __shared__ float bnl[512];                // (s,o) pairs for 256 outs
    const int tid  = threadIdx.x;
    const int lane = tid & 63;
    const int n    = lane & 15;
    const int quad = lane >> 4;
    const int wv   = tid >> 6;
    const int pix0 = blockIdx.x * 64;
    const int b    = pix0 / HWsz;
    const int hw0  = pix0 - b * HWsz;

    // stage out2b tile: thread (px=tid&63, ck=tid>>6) loads chunks ck, ck+4
    {
        const int px = tid & 63;
        const int ck = tid >> 6;
        const unsigned short* ob = out2b + ((size_t)b * HWsz + hw0 + px) * 64;
        const uint4 v0 = *reinterpret_cast<const uint4*>(ob + ck * 8);
        const uint4 v1 = *reinterpret_cast<const uint4*>(ob + (ck + 4) * 8);
        *reinterpret_cast<uint4*>(bls + px * 72 + ck * 8)       = v0;
        *reinterpret_cast<uint4*>(bls + px * 72 + (ck + 4) * 8) = v1;
        bnl[tid * 2]     = bn3s[tid];
        bnl[tid * 2 + 1] = bn3o[tid];
    }
    __syncthreads();

    short8 bf[2];
#pragma unroll
    for (int ks = 0; ks < 2; ++ks)
        bf[ks] = *reinterpret_cast<const short8*>(bls + (wv * 16 + n) * 72 + ks * 32 + quad * 8);

    const floatx4 zero = {0.f, 0.f, 0.f, 0.f};
    floatx4 acc[16];
#pragma unroll
    for (int mb = 0; mb < 16; ++mb) acc[mb] = zero;

    const uint4* wp = reinterpret_cast<const uint4*>(w3p);
#pragma unroll
    for (int mb = 0; mb < 16; ++mb) {
        const short8 a0 = as_short8(wp[(mb * 2 + 0) * 64 + lane]);
        const short8 a1 = as_short8(wp[(mb * 2 + 1) * 64 + lane]);
        acc[mb] = __builtin_amdgcn_mfma_f32_16x16x32_bf16(a0, bf[0], acc[mb], 0, 0, 0);
        acc[mb] = __builtin_amdgcn_mfma_f32_16x16x32_bf16(a1, bf[1], acc[mb], 0, 0, 0);
    }

    // epilogue: BN3 + residual + ReLU
    const int colg = hw0 + wv * 16 + n;
#pragma unroll
    for (int mb = 0; mb < 16; ++mb) {
#pragma unroll
        for (int r = 0; r < 4; ++r) {
            const int o = mb * 16 + quad * 4 + r;
            const float2 so = *reinterpret_cast<const float2*>(&bnl[o * 2]);
            const size_t gi = ((size_t)b * 256 + o) * HWsz + colg;
            const float val = fmaf(acc[mb][r], so.x, so.y) + x[gi];
            out[gi] = fmaxf(val, 0.f);
        }
    }
}

extern "C" void kernel_launch(void* const* d_in, const int* in_sizes, int n_in,
                              void* d_out, int out_size, void* d_ws, size_t ws_size,
                              hipStream_t stream)
{
    const float* x    = (const float*)d_in[0];
    const float* w1   = (const float*)d_in[1];
    const float* bn1g = (const float*)d_in[2];
    const float* bn1b = (const float*)d_in[3];
    const float* bn1m = (const float*)d_in[4];
    const float* bn1v = (const float*)d_in[5];
    const float* c1w  = (const float*)d_in[6];
    const float* ibg  = (const float*)d_in[7];
    const float* ibb  = (const float*)d_in[8];
    const float* ibm  = (const float*)d_in[9];
    const float* ibv  = (const float*)d_in[10];
    const float* c2w  = (const float*)d_in[11];
    const float* c2b  = (const float*)d_in[12];
    const float* bn2g = (const float*)d_in[13];
    const float* bn2b = (const float*)d_in[14];
    const float* bn2m = (const float*)d_in[15];
    const float* bn2v = (const float*)d_in[16];
    const float* w3   = (const float*)d_in[17];
    const float* bn3g = (const float*)d_in[18];
    const float* bn3b = (const float*)d_in[19];
    const float* bn3m = (const float*)d_in[20];
    const float* bn3v = (const float*)d_in[21];

    // ws layout (float units)
    float* wsf = (float*)d_ws;
    float*          out1  = wsf;                                  // 3211264
    unsigned short* out2b = (unsigned short*)(wsf + 3211264);     // 3211264 us
    float*          tbuf  = wsf + 4816896;                        // 802816
    unsigned short* w1p   = (unsigned short*)(wsf + 5619712);     // 16384 us
    unsigned short* w3p   = (unsigned short*)(wsf + 5627904);     // 16384 us
    unsigned short* c1wp  = (unsigned short*)(wsf + 5636096);     // 1024 us
    float* bn1s = wsf + 5636608; float* bn1o = wsf + 5636672;
    float* ibs  = wsf + 5636736; float* ibo  = wsf + 5636752;
    float* bn2s = wsf + 5636768; float* bn2o = wsf + 5636832;
    float* bn3s = wsf + 5636896; float* bn3o = wsf + 5637152;

    prep<<<dim3(64), dim3(256), 0, stream>>>(
        w1, w3, c1w, bn1g, bn1b, bn1m, bn1v, ibg, ibb, ibm, ibv,
        bn2g, bn2b, bn2m, bn2v, bn3g, bn3b, bn3m, bn3v,
        w1p, w3p, c1wp, bn1s, bn1o, ibs, ibo, bn2s, bn2o, bn3s, bn3o);

    k1_conv1_branch<<<dim3(784), dim3(256), 0, stream>>>(
        x, w1p, bn1s, bn1o, c1wp, ibs, ibo, out1, tbuf);

    k2_involution<<<dim3(7, 64, 2), dim3(448), 0, stream>>>(
        out1, tbuf, c2w, c2b, bn2s, bn2o, out2b);

    k3_conv3<<<dim3(784), dim3(256), 0, stream>>>(
        out2b, x, w3p, bn3s, bn3o, (float*)d_out);
}